// Round 5
// baseline (297.892 us; speedup 1.0000x reference)
//
#include <hip/hip_runtime.h>
#include <stdint.h>
#include <math.h>

#define B_ 4
#define S_ 1024
#define E_ 1024
#define H_ 16
#define HD_ 64
#define HB_ 64  // H_*B_

typedef __attribute__((ext_vector_type(8))) short bhalf8;
typedef __attribute__((ext_vector_type(4))) float floatx4;

__device__ __forceinline__ unsigned short f2bf(float f) {
  union { float f; unsigned u; } v; v.f = f;
  unsigned r = (v.u + 0x7FFFu + ((v.u >> 16) & 1u)) >> 16;
  return (unsigned short)r;
}
__device__ __forceinline__ float bf2f(unsigned short b) {
  union { unsigned u; float f; } v; v.u = ((unsigned)b) << 16;
  return v.f;
}
__device__ __forceinline__ unsigned short f2h(float f) {
  union { _Float16 h; unsigned short u; } v; v.h = (_Float16)f; return v.u;
}
__device__ __forceinline__ float h2f(unsigned short u) {
  union { unsigned short u; _Float16 h; } v; v.u = u; return (float)v.h;
}

__device__ __forceinline__ void gload16(const void* g, void* l) {
  __builtin_amdgcn_global_load_lds(
      (const __attribute__((address_space(1))) unsigned int*)g,
      (__attribute__((address_space(3))) unsigned int*)l, 16, 0, 0);
}

// Stage NCH*8 rows x 64 bf16 (128B rows, global row stride 1024 elems) into
// LDS, linear dest + inverse-swizzled source (involution: byte ^= (row&7)<<4).
template <int NCH>
__device__ __forceinline__ void stage_tile(const unsigned short* org,
                                           unsigned short* lds, int wave, int lane) {
  const int rl = lane >> 3;                      // row within 8-row chunk
  const int scb = ((lane & 7) << 4) ^ (rl << 4); // pre-swizzled source col byte
  const char* base = (const char*)org + scb;
#pragma unroll
  for (int i = 0; i < NCH / 4; ++i) {
    const int c = wave + 4 * i;
    gload16(base + (size_t)(c * 8 + rl) * 2048, (char*)lds + c * 1024);
  }
}

// Read one MFMA operand fragment (8 contiguous bf16) with the matching swizzle.
__device__ __forceinline__ bhalf8 read_frag(const unsigned short* lds, int row, int kbyte) {
  const int off = row * 128 + (kbyte ^ ((row & 7) << 4));
  return *(const bhalf8*)((const char*)lds + off);
}

// ---------------------------------------------------------------------------
__global__ void detect_bool_kernel(const uint8_t* __restrict__ amask, int* __restrict__ flag) {
  if (threadIdx.x == 0 && blockIdx.x == 0) *flag = (amask[1] != 0) ? 1 : 0;
}

// fp32 -> bf16 for the 3 activation inputs (z selects tensor)
__global__ __launch_bounds__(256) void cvt_in_kernel(
    const float* __restrict__ q, const float* __restrict__ k,
    const float* __restrict__ v, unsigned short* __restrict__ Ab) {
  const int z = blockIdx.z;
  const float* src = (z == 0) ? q : (z == 1) ? k : v;
  unsigned short* dst = Ab + (size_t)z * 4194304;
  const size_t i = ((size_t)blockIdx.x * 256 + threadIdx.x) * 8;
  float4 a = *(const float4*)(src + i);
  float4 b = *(const float4*)(src + i + 4);
  bhalf8 r;
  r[0] = (short)f2bf(a.x); r[1] = (short)f2bf(a.y);
  r[2] = (short)f2bf(a.z); r[3] = (short)f2bf(a.w);
  r[4] = (short)f2bf(b.x); r[5] = (short)f2bf(b.y);
  r[6] = (short)f2bf(b.z); r[7] = (short)f2bf(b.w);
  *(bhalf8*)(dst + i) = r;
}

// fp32 -> bf16 for the 4 weight matrices
__global__ __launch_bounds__(256) void cvt_w_kernel(
    const float* __restrict__ wq, const float* __restrict__ wk,
    const float* __restrict__ wv, const float* __restrict__ wo,
    unsigned short* __restrict__ Wb) {
  const int z = blockIdx.z;
  const float* src = (z == 0) ? wq : (z == 1) ? wk : (z == 2) ? wv : wo;
  unsigned short* dst = Wb + (size_t)z * 1048576;
  const size_t i = ((size_t)blockIdx.x * 256 + threadIdx.x) * 8;
  float4 a = *(const float4*)(src + i);
  float4 b = *(const float4*)(src + i + 4);
  bhalf8 r;
  r[0] = (short)f2bf(a.x); r[1] = (short)f2bf(a.y);
  r[2] = (short)f2bf(a.z); r[3] = (short)f2bf(a.w);
  r[4] = (short)f2bf(b.x); r[5] = (short)f2bf(b.y);
  r[6] = (short)f2bf(b.z); r[7] = (short)f2bf(b.w);
  *(bhalf8*)(dst + i) = r;
}

// ---------------------------------------------------------------------------
// C[4096,1024] = A @ W^T + bias. 128x128 tile, BK=64, 4 waves (2x2 quadrants).
// XCD-chunked swizzle on the 256-block (x,y) grid for L2 locality.
// ---------------------------------------------------------------------------
template <bool BF16OUT>
__global__ __launch_bounds__(256) void mfma_gemm_kernel(
    const unsigned short* __restrict__ A0, const unsigned short* __restrict__ A1,
    const unsigned short* __restrict__ A2,
    const unsigned short* __restrict__ W0, const unsigned short* __restrict__ W1,
    const unsigned short* __restrict__ W2,
    const float* __restrict__ b0, const float* __restrict__ b1,
    const float* __restrict__ b2,
    void* __restrict__ C0, void* __restrict__ C1, void* __restrict__ C2) {
  const int z = blockIdx.z;
  const unsigned short* A = (z == 0) ? A0 : (z == 1) ? A1 : A2;
  const unsigned short* W = (z == 0) ? W0 : (z == 1) ? W1 : W2;
  const float* bias = (z == 0) ? b0 : (z == 1) ? b1 : b2;
  void* C = (z == 0) ? C0 : (z == 1) ? C1 : C2;
  const int lin = blockIdx.y * 8 + blockIdx.x;
  const int swz = (lin & 7) * 32 + (lin >> 3);
  const int m0 = (swz >> 3) * 128, n0 = (swz & 7) * 128;
  __shared__ unsigned short As[128 * 64];
  __shared__ unsigned short Ws[128 * 64];
  const int t = threadIdx.x, wave = t >> 6, lane = t & 63;
  const int wr = wave >> 1, wc = wave & 1;
  floatx4 acc[4][4];
  const floatx4 z4 = {0.f, 0.f, 0.f, 0.f};
#pragma unroll
  for (int i = 0; i < 4; ++i)
#pragma unroll
    for (int j = 0; j < 4; ++j) acc[i][j] = z4;

  for (int k0 = 0; k0 < 1024; k0 += 64) {
    stage_tile<16>(A + (size_t)m0 * 1024 + k0, As, wave, lane);
    stage_tile<16>(W + (size_t)n0 * 1024 + k0, Ws, wave, lane);
    __syncthreads();
#pragma unroll
    for (int ks = 0; ks < 2; ++ks) {
      const int kb = ks * 64 + ((lane >> 4) << 4);
      bhalf8 af[4], bf[4];
#pragma unroll
      for (int mi = 0; mi < 4; ++mi)
        af[mi] = read_frag(As, wr * 64 + mi * 16 + (lane & 15), kb);
#pragma unroll
      for (int ni = 0; ni < 4; ++ni)
        bf[ni] = read_frag(Ws, wc * 64 + ni * 16 + (lane & 15), kb);
#pragma unroll
      for (int mi = 0; mi < 4; ++mi)
#pragma unroll
        for (int ni = 0; ni < 4; ++ni)
          acc[mi][ni] = __builtin_amdgcn_mfma_f32_16x16x32_bf16(af[mi], bf[ni], acc[mi][ni], 0, 0, 0);
    }
    __syncthreads();
  }
#pragma unroll
  for (int mi = 0; mi < 4; ++mi)
#pragma unroll
    for (int ni = 0; ni < 4; ++ni) {
      const int col = n0 + wc * 64 + ni * 16 + (lane & 15);
      const float bv = bias[col];
#pragma unroll
      for (int r = 0; r < 4; ++r) {
        const int row = m0 + wr * 64 + mi * 16 + (lane >> 4) * 4 + r;
        const float v = acc[mi][ni][r] + bv;
        if (BF16OUT)
          ((unsigned short*)C)[(size_t)row * 1024 + col] = f2bf(v);
        else
          ((float*)C)[(size_t)row * 1024 + col] = v;
      }
    }
}

// ---------------------------------------------------------------------------
// In-place RoPE on bf16 [B,S,E]; one thread per channel pair.
// ---------------------------------------------------------------------------
__global__ __launch_bounds__(256) void rope_bf_kernel(unsigned int* __restrict__ X,
                                                      const int* __restrict__ idxs) {
  const int gid = blockIdx.x * 256 + threadIdx.x;
  const int i = gid & 511, bs = gid >> 9;
  const int pos = idxs[bs];
  const double freq = exp(-(double)(2 * i) * (9.210340371976184 / 1024.0));
  const double ang = fmod((double)pos * freq, 6.283185307179586476925287);
  const float fa = (float)ang;
  float sn, c;
  sincosf(fa, &sn, &c);
  const unsigned v = X[gid];
  const float x = bf2f((unsigned short)(v & 0xffffu));
  const float y = bf2f((unsigned short)(v >> 16));
  const float rx = x * c - y * sn;
  const float ry = x * sn + y * c;
  X[gid] = (unsigned)f2bf(rx) | ((unsigned)f2bf(ry) << 16);
}

// ---------------------------------------------------------------------------
// Vt[(b*16+h)*64 + d][s] = Vr[b][s][h*64+d]   (bf16 transpose, 64x64 tiles)
// ---------------------------------------------------------------------------
__global__ __launch_bounds__(256) void transpose_v_kernel(
    const unsigned short* __restrict__ Vr, unsigned short* __restrict__ Vt) {
  const int s0 = blockIdx.x * 64;
  const int bh = blockIdx.y;
  const int b = bh >> 4, h = bh & 15;
  __shared__ unsigned short L[64][72];
  const int t = threadIdx.x, r = t >> 2, cq = (t & 3) * 16;
  const unsigned short* src = Vr + ((size_t)(b * S_) + s0 + r) * E_ + h * HD_ + cq;
  *(bhalf8*)&L[r][cq] = *(const bhalf8*)src;
  *(bhalf8*)&L[r][cq + 8] = *(const bhalf8*)(src + 8);
  __syncthreads();
  bhalf8 o0, o1;
#pragma unroll
  for (int u = 0; u < 8; ++u) o0[u] = (short)L[cq + u][r];
#pragma unroll
  for (int u = 0; u < 8; ++u) o1[u] = (short)L[cq + 8 + u][r];
  unsigned short* dst = Vt + ((size_t)bh * 64 + r) * 1024 + s0 + cq;
  *(bhalf8*)dst = o0;
  *(bhalf8*)(dst + 8) = o1;
}

// ---------------------------------------------------------------------------
// Fully fused attention middle: QK^T -> masked softmax -> wmean partial -> PV.
// One block per (16 q-rows, batch b, head-group hg); nh heads per group.
// P never goes to global. 512 threads (8 waves), 36KB LDS.
//   QK^T: swapped operands (A=K rows, B=Q rows); wave w owns k in [w*128,+128).
//   S spilled to XOR-swizzled f16 LDS; softmax: wave w owns rows {2w, 2w+1};
//   P written back in place as bf16; PV: wave w = (d-quarter w&3, k-half w>>2),
//   cross-wave pair-reduce through a 4KB LDS buffer.
// ---------------------------------------------------------------------------
__global__ __launch_bounds__(512) void attn_fused_kernel(
    const unsigned short* __restrict__ Qr, const unsigned short* __restrict__ Kr,
    const unsigned short* __restrict__ Vt, unsigned short* __restrict__ Ocat,
    float* __restrict__ Wpart, const void* __restrict__ amask,
    const void* __restrict__ kpm, const int* __restrict__ flagp,
    int nh, float wscale) {
  const int qb = blockIdx.x, b = blockIdx.y, hg = blockIdx.z;
  const int q0 = qb * 16;
  const int t = threadIdx.x, w = t >> 6, lane = t & 63;
  const int l4 = lane >> 4, l15 = lane & 15;
  __shared__ unsigned short Sbuf[16 * 1024];  // f16 S, then bf16 P in place
  __shared__ float Red[1024];                 // PV cross-wave reduction

  const int isu8 = *flagp;

  // --- masks once per block; k-mapping: k = j*512 + lane*8 + u ---
  unsigned am_bits[2];
#pragma unroll
  for (int r = 0; r < 2; ++r) {
    const int gq = q0 + w * 2 + r;
    unsigned mb = 0;
    if (isu8) {
      const uint8_t* ap = (const uint8_t*)amask + (size_t)gq * 1024;
#pragma unroll
      for (int j = 0; j < 2; ++j) {
        uint2 v = *(const uint2*)(ap + j * 512 + lane * 8);
#pragma unroll
        for (int u = 0; u < 4; ++u) {
          if ((v.x >> (8 * u)) & 0xffu) mb |= 1u << (j * 8 + u);
          if ((v.y >> (8 * u)) & 0xffu) mb |= 1u << (j * 8 + 4 + u);
        }
      }
    } else {
      const int* ap = (const int*)amask + (size_t)gq * 1024;
#pragma unroll
      for (int j = 0; j < 2; ++j) {
        int4 v0 = *(const int4*)(ap + j * 512 + lane * 8);
        int4 v1 = *(const int4*)(ap + j * 512 + lane * 8 + 4);
        if (v0.x) mb |= 1u << (j * 8 + 0);
        if (v0.y) mb |= 1u << (j * 8 + 1);
        if (v0.z) mb |= 1u << (j * 8 + 2);
        if (v0.w) mb |= 1u << (j * 8 + 3);
        if (v1.x) mb |= 1u << (j * 8 + 4);
        if (v1.y) mb |= 1u << (j * 8 + 5);
        if (v1.z) mb |= 1u << (j * 8 + 6);
        if (v1.w) mb |= 1u << (j * 8 + 7);
      }
    }
    am_bits[r] = mb;
  }
  unsigned km_bits[4];
#pragma unroll
  for (int bp = 0; bp < 4; ++bp) {
    unsigned mb = 0;
    if (isu8) {
      const uint8_t* kp = (const uint8_t*)kpm + (size_t)bp * 1024;
#pragma unroll
      for (int j = 0; j < 2; ++j) {
        uint2 v = *(const uint2*)(kp + j * 512 + lane * 8);
#pragma unroll
        for (int u = 0; u < 4; ++u) {
          if ((v.x >> (8 * u)) & 0xffu) mb |= 1u << (j * 8 + u);
          if ((v.y >> (8 * u)) & 0xffu) mb |= 1u << (j * 8 + 4 + u);
        }
      }
    } else {
      const int* kp = (const int*)kpm + (size_t)bp * 1024;
#pragma unroll
      for (int j = 0; j < 2; ++j) {
        int4 v0 = *(const int4*)(kp + j * 512 + lane * 8);
        int4 v1 = *(const int4*)(kp + j * 512 + lane * 8 + 4);
        if (v0.x) mb |= 1u << (j * 8 + 0);
        if (v0.y) mb |= 1u << (j * 8 + 1);
        if (v0.z) mb |= 1u << (j * 8 + 2);
        if (v0.w) mb |= 1u << (j * 8 + 3);
        if (v1.x) mb |= 1u << (j * 8 + 4);
        if (v1.y) mb |= 1u << (j * 8 + 5);
        if (v1.z) mb |= 1u << (j * 8 + 6);
        if (v1.w) mb |= 1u << (j * 8 + 7);
      }
    }
    km_bits[bp] = mb;
  }

  float wacc[2][16];
#pragma unroll
  for (int r = 0; r < 2; ++r)
#pragma unroll
    for (int i = 0; i < 16; ++i) wacc[r][i] = 0.f;

  const floatx4 z4 = {0.f, 0.f, 0.f, 0.f};
  const float Cc = 0.18033688011112042f;  // 0.125 * log2(e)

  for (int hh = 0; hh < nh; ++hh) {
    const int h = hg * nh + hh;
    const char* Qb = (const char*)Qr + ((size_t)b << 21) + h * 128;
    const char* Kb = (const char*)Kr + ((size_t)b << 21) + h * 128;

    // Q fragments (B-operand; rows q0+l15)
    bhalf8 bq0 = *(const bhalf8*)(Qb + (size_t)(q0 + l15) * 2048 + l4 * 16);
    bhalf8 bq1 = *(const bhalf8*)(Qb + (size_t)(q0 + l15) * 2048 + 64 + l4 * 16);

    // QK^T: wave w covers k in [w*128, w*128+128)
    floatx4 acc[8];
#pragma unroll
    for (int i = 0; i < 8; ++i) acc[i] = z4;
#pragma unroll
    for (int mt = 0; mt < 8; ++mt) {
      const char* kr = Kb + (size_t)(w * 128 + mt * 16 + l15) * 2048 + l4 * 16;
      bhalf8 a0 = *(const bhalf8*)kr;
      bhalf8 a1 = *(const bhalf8*)(kr + 64);
      acc[mt] = __builtin_amdgcn_mfma_f32_16x16x32_bf16(a0, bq0, acc[mt], 0, 0, 0);
      acc[mt] = __builtin_amdgcn_mfma_f32_16x16x32_bf16(a1, bq1, acc[mt], 0, 0, 0);
    }
    // Spill raw S (f16): lane owns q=l15, k = w*128 + mt*16 + l4*4 + r
    {
      const int xr = (l15 & 7) << 4;
#pragma unroll
      for (int mt = 0; mt < 8; ++mt) {
        const int kb2 = (w * 128 + mt * 16 + l4 * 4) * 2;
        ushort4 hv;
        hv.x = f2h(acc[mt][0]); hv.y = f2h(acc[mt][1]);
        hv.z = f2h(acc[mt][2]); hv.w = f2h(acc[mt][3]);
        *(ushort4*)((char*)Sbuf + l15 * 2048 + (kb2 ^ xr)) = hv;
      }
    }
    __syncthreads();

    // Softmax on rows {2w, 2w+1}; write P back in place (bf16); wmean acc.
    const unsigned kmb = km_bits[h >> 2];
#pragma unroll
    for (int r = 0; r < 2; ++r) {
      const int ql = w * 2 + r;
      const int xr = (ql & 7) << 4;
      float x[16];
#pragma unroll
      for (int j = 0; j < 2; ++j) {
        bhalf8 hv = *(const bhalf8*)((const char*)Sbuf + ql * 2048 +
                                     ((j * 1024 + lane * 16) ^ xr));
#pragma unroll
        for (int u = 0; u < 8; ++u) x[j * 8 + u] = h2f((unsigned short)hv[u]);
      }
      const unsigned mb = am_bits[r] | kmb;
#pragma unroll
      for (int i = 0; i < 16; ++i)
        if ((mb >> i) & 1u) x[i] = -INFINITY;
      float m = x[0];
#pragma unroll
      for (int i = 1; i < 16; ++i) m = fmaxf(m, x[i]);
#pragma unroll
      for (int o = 32; o > 0; o >>= 1) m = fmaxf(m, __shfl_xor(m, o));
      const float mc = m * Cc;
      float s = 0.f;
#pragma unroll
      for (int i = 0; i < 16; ++i) {
        x[i] = exp2f(__builtin_fmaf(x[i], Cc, -mc));
        s += x[i];
      }
#pragma unroll
      for (int o = 32; o > 0; o >>= 1) s += __shfl_xor(s, o);
      const float inv = 1.0f / s;
#pragma unroll
      for (int j = 0; j < 2; ++j) {
        bhalf8 pv;
#pragma unroll
        for (int u = 0; u < 8; ++u) {
          const float p = x[j * 8 + u] * inv;
          pv[u] = (short)f2bf(p);
          wacc[r][j * 8 + u] += p;
        }
        *(bhalf8*)((char*)Sbuf + ql * 2048 + ((j * 1024 + lane * 16) ^ xr)) = pv;
      }
    }
    __syncthreads();

    // PV: wave w -> d-quarter dq = w&3, k-half kh = w>>2.
    const int dq = w & 3, kh = w >> 2;
    floatx4 o4 = z4;
    const char* Vb = (const char*)Vt +
        (((size_t)(b * 16 + h) * 64 + dq * 16 + l15) * 1024 + kh * 512) * 2;
    const int xrp = (l15 & 7) << 4;
#pragma unroll
    for (int kt = 0; kt < 16; ++kt) {
      bhalf8 pa = *(const bhalf8*)((const char*)Sbuf + l15 * 2048 +
                                   ((kh * 1024 + kt * 64 + l4 * 16) ^ xrp));
      bhalf8 vb = *(const bhalf8*)(Vb + kt * 64 + l4 * 16);
      o4 = __builtin_amdgcn_mfma_f32_16x16x32_bf16(pa, vb, o4, 0, 0, 0);
    }
    if (kh == 1) *(floatx4*)&Red[dq * 256 + lane * 4] = o4;
    __syncthreads();
    if (kh == 0) {
      const floatx4 p4 = *(const floatx4*)&Red[dq * 256 + lane * 4];
#pragma unroll
      for (int r2 = 0; r2 < 4; ++r2) {
        const int q = q0 + l4 * 4 + r2;
        Ocat[((size_t)(b * 1024) + q) * 1024 + h * 64 + dq * 16 + l15] =
            f2bf(o4[r2] + p4[r2]);
      }
    }
  }

  // wmean partial write: plane = hg*4 + b
  const int plane = hg * 4 + b;
  float* wp = Wpart + ((size_t)plane << 20);
#pragma unroll
  for (int r = 0; r < 2; ++r) {
    const int gq = q0 + w * 2 + r;
    float* row = wp + ((size_t)gq << 10);
#pragma unroll
    for (int j = 0; j < 2; ++j) {
      float4 v0, v1;
      v0.x = wacc[r][j * 8 + 0] * wscale; v0.y = wacc[r][j * 8 + 1] * wscale;
      v0.z = wacc[r][j * 8 + 2] * wscale; v0.w = wacc[r][j * 8 + 3] * wscale;
      v1.x = wacc[r][j * 8 + 4] * wscale; v1.y = wacc[r][j * 8 + 5] * wscale;
      v1.z = wacc[r][j * 8 + 6] * wscale; v1.w = wacc[r][j * 8 + 7] * wscale;
      *(float4*)(row + j * 512 + lane * 8) = v0;
      *(float4*)(row + j * 512 + lane * 8 + 4) = v1;
    }
  }
}

// ---------------------------------------------------------------------------
// outW = (Wp0 + Wp1) / 16   over 4M floats
// ---------------------------------------------------------------------------
__global__ __launch_bounds__(256) void wreduce_kernel(
    const float* __restrict__ w0, const float* __restrict__ w1,
    float* __restrict__ out) {
  const size_t i = ((size_t)blockIdx.x * 256 + threadIdx.x) * 8;
  const float s = 1.0f / 16.0f;
  float4 a0 = *(const float4*)(w0 + i), a1 = *(const float4*)(w0 + i + 4);
  float4 b0 = *(const float4*)(w1 + i), b1 = *(const float4*)(w1 + i + 4);
  float4 r0, r1;
  r0.x = (a0.x + b0.x) * s; r0.y = (a0.y + b0.y) * s;
  r0.z = (a0.z + b0.z) * s; r0.w = (a0.w + b0.w) * s;
  r1.x = (a1.x + b1.x) * s; r1.y = (a1.y + b1.y) * s;
  r1.z = (a1.z + b1.z) * s; r1.w = (a1.w + b1.w) * s;
  *(float4*)(out + i) = r0;
  *(float4*)(out + i + 4) = r1;
}

// ---------------------------------------------------------------------------
extern "C" void kernel_launch(void* const* d_in, const int* in_sizes, int n_in,
                              void* d_out, int out_size, void* d_ws, size_t ws_size,
                              hipStream_t stream) {
  (void)in_sizes; (void)n_in; (void)out_size;
  const float* query = (const float*)d_in[0];
  const float* key   = (const float*)d_in[1];
  const float* value = (const float*)d_in[2];
  const int* qidx = (const int*)d_in[3];
  const int* kidx = (const int*)d_in[4];
  const void* amask = d_in[5];
  const void* kpm   = d_in[6];
  const float* Wq = (const float*)d_in[7];
  const float* bq = (const float*)d_in[8];
  const float* Wk = (const float*)d_in[9];
  const float* bk = (const float*)d_in[10];
  const float* Wv = (const float*)d_in[11];
  const float* bv = (const float*)d_in[12];
  const float* Wo = (const float*)d_in[13];
  const float* bo = (const float*)d_in[14];

  float* outA = (float*)d_out;                          // [B,S,E] fp32
  float* outW = (float*)d_out + (size_t)B_ * S_ * E_;   // [B,S,S] fp32

  float* ws = (float*)d_ws;
  unsigned short* Ab   = (unsigned short*)(ws + 0);         // 3x 4,194,304 bf16
  unsigned short* Wb   = (unsigned short*)(ws + 6291456);   // 4x 1,048,576 bf16
  unsigned short* Qr   = (unsigned short*)(ws + 8388608);
  unsigned short* Kr   = (unsigned short*)(ws + 10485760);
  unsigned short* Vr   = (unsigned short*)(ws + 12582912);
  unsigned short* Vt   = (unsigned short*)(ws + 14680064);
  unsigned short* Ocat = (unsigned short*)(ws + 16777216);
  int* flagp           = (int*)(ws + 18874368);
  const size_t tail_off = 18874432;  // floats

  // Head-mean partials: 2 groups x [4][S][S] fp32 = 8,388,608 floats (32 MB).
  const size_t ws_floats = ws_size / 4;
  const bool hg2 = (tail_off + 8388608ull <= ws_floats);
  float* Wpart = hg2 ? (ws + tail_off) : outW;

  detect_bool_kernel<<<1, 64, 0, stream>>>((const uint8_t*)amask, flagp);

  cvt_in_kernel<<<dim3(2048, 1, 3), 256, 0, stream>>>(query, key, value, Ab);
  cvt_w_kernel<<<dim3(512, 1, 4), 256, 0, stream>>>(Wq, Wk, Wv, Wo, Wb);

  mfma_gemm_kernel<true><<<dim3(8, 32, 3), 256, 0, stream>>>(
      Ab, Ab + 4194304, Ab + 8388608,
      Wb, Wb + 1048576, Wb + 2097152,
      bq, bk, bv, Qr, Kr, Vr);

  rope_bf_kernel<<<8192, 256, 0, stream>>>((unsigned int*)Qr, qidx);
  rope_bf_kernel<<<8192, 256, 0, stream>>>((unsigned int*)Kr, kidx);

  transpose_v_kernel<<<dim3(16, 64), 256, 0, stream>>>(Vr, Vt);

  if (hg2) {
    attn_fused_kernel<<<dim3(64, 4, 2), 512, 0, stream>>>(
        Qr, Kr, Vt, Ocat, Wpart, amask, kpm, flagp, 8, 1.0f);
    wreduce_kernel<<<2048, 256, 0, stream>>>(Wpart, Wpart + 4194304, outW);
  } else {
    // Single group: 16 heads per block, write outW directly with the /16.
    attn_fused_kernel<<<dim3(64, 4, 1), 512, 0, stream>>>(
        Qr, Kr, Vt, Ocat, Wpart, amask, kpm, flagp, 16, 1.0f / 16.0f);
  }

  mfma_gemm_kernel<false><<<dim3(8, 32, 1), 256, 0, stream>>>(
      Ocat, Ocat, Ocat, Wb + 3145728, Wb + 3145728, Wb + 3145728,
      bo, bo, bo, outA, outA, outA);
}